// Round 16
// baseline (308.010 us; speedup 1.0000x reference)
//
#include <hip/hip_runtime.h>
#include <cstdint>

#define N_ANCH 8400
#define CBLK 132              // ceil(8400/64)
#define SCORE_THR 0.5f
#define NDIAG 8               // wlo_t diagonals 0..7

typedef unsigned long long u64;
typedef unsigned int u32;

// Sort key: ascending sort == (valid score descending, then index ascending,
// invalid last by index ascending) — exactly matches
// argsort(-where(valid, s, -inf)) with stable ties.
__device__ __forceinline__ u64 sort_key(float s, int idx) {
  u32 k32 = (s >= SCORE_THR) ? ~__float_as_uint(s) : 0xFFFFFFFFu;
  return ((u64)k32 << 32) | (u32)idx;
}

// Force a wave-uniform u64 into SGPRs.
__device__ __forceinline__ u64 rfl64(u64 v) {
  u32 lo = (u32)__builtin_amdgcn_readfirstlane((int)(u32)v);
  u32 hi = (u32)__builtin_amdgcn_readfirstlane((int)(u32)(v >> 32));
  return ((u64)hi << 32) | lo;
}

// 4 rows per wave; scores scanned as float4 (33 iters, 4x fewer loads).
__global__ void __launch_bounds__(256) rank_kernel(const float* __restrict__ raw,
                                                   float4* __restrict__ sbox,
                                                   float* __restrict__ sscore) {
  #pragma clang fp contract(off)
  int tid = blockIdx.x * 256 + threadIdx.x;
  int wid = tid >> 6, lane = tid & 63;
  int base = wid * 4;                            // 525 blocks -> base <= 8396
  const float* sc = raw + 4 * N_ANCH;
  float4 sv = *(const float4*)(sc + base);       // wave-uniform broadcast load
  u64 k0 = sort_key(sv.x, base),     k1 = sort_key(sv.y, base + 1);
  u64 k2 = sort_key(sv.z, base + 2), k3 = sort_key(sv.w, base + 3);
  int c0 = 0, c1 = 0, c2 = 0, c3 = 0;
  for (int it = 0; it < 33; ++it) {
    int j = it * 256 + (lane << 2);              // multiple of 4; j+3 <= 8399
    if (j < N_ANCH) {
      float4 q = *(const float4*)(sc + j);
      u64 a0 = sort_key(q.x, j),     a1 = sort_key(q.y, j + 1);
      u64 a2 = sort_key(q.z, j + 2), a3 = sort_key(q.w, j + 3);
      c0 += (a0 < k0) + (a1 < k0) + (a2 < k0) + (a3 < k0);
      c1 += (a0 < k1) + (a1 < k1) + (a2 < k1) + (a3 < k1);
      c2 += (a0 < k2) + (a1 < k2) + (a2 < k2) + (a3 < k2);
      c3 += (a0 < k3) + (a1 < k3) + (a2 < k3) + (a3 < k3);
    }
  }
  #pragma unroll
  for (int d = 1; d < 64; d <<= 1) {
    c0 += __shfl_xor(c0, d, 64); c1 += __shfl_xor(c1, d, 64);
    c2 += __shfl_xor(c2, d, 64); c3 += __shfl_xor(c3, d, 64);
  }
  if (lane < 4) {
    int row = base + lane;
    int cnt = (lane == 0) ? c0 : (lane == 1) ? c1 : (lane == 2) ? c2 : c3;
    float s = (lane == 0) ? sv.x : (lane == 1) ? sv.y : (lane == 2) ? sv.z : sv.w;
    float cx = raw[row], cy = raw[N_ANCH + row];
    float w = raw[2 * N_ANCH + row], h = raw[3 * N_ANCH + row];
    float hw = w * 0.5f, hh = h * 0.5f;
    sbox[cnt] = make_float4(cx - hw, cy - hh, cx + hw, cy + hh);
    sscore[cnt] = s;
  }
}

// Suppression bitmask, two output layouts; only the NEEDED word per cell
// (R14 form, ~25% less inner-loop VALU):
//   ABOVE diagonal (cb > i>>6): wHi (row word, "boxes I suppress") in
//     mask[i*CBLK+cb]. Read by nms consume (distance >= 8).
//   NEAR diagonal (0 <= d = (i>>6)-cb <= 7): wLo (COLUMN word) TRANSPOSED
//     in wlo_t[d][i>>6][i&63] — contiguous in lane (4 lines per wave0 read).
//   d > 7: dead (band skip).
__global__ void __launch_bounds__(256) mask_kernel(const float4* __restrict__ sbox,
                                                   const float* __restrict__ sscore,
                                                   u64* __restrict__ mask,
                                                   u64* __restrict__ wlo_t) {
  #pragma clang fp contract(off)
  int cb = blockIdx.x;
  int i0 = blockIdx.y * 256;
  if (cb + 7 < (i0 >> 6)) return;                // below-diagonal band skip
  if (!(sscore[i0] >= SCORE_THR)) return;        // whole row-block invalid
  if (!(sscore[cb * 64] >= SCORE_THR)) return;   // whole col-block invalid
  int t = threadIdx.x;
  __shared__ float4 cbox[64];
  __shared__ float carea[64];
  int j0 = cb * 64;
  if (t < 64) {
    int j = j0 + t;
    float4 bj = (j < N_ANCH) ? sbox[j] : make_float4(0.f, 0.f, 0.f, 0.f);
    cbox[t] = bj;
    carea[t] = (bj.z - bj.x) * (bj.w - bj.y);
  }
  __syncthreads();
  int i = i0 + t;
  if (i >= N_ANCH) return;
  int rb = i >> 6;
  int d = rb - cb;
  if (d >= NDIAG) return;                        // thread-level band skip
  bool hi = (d < 0);                             // which word this cell needs
  float4 bi = sbox[i];
  float ai = (bi.z - bi.x) * (bi.w - bi.y);
  u64 w = 0;
  for (int jj = 0; jj < 64; ++jj) {
    int jg = j0 + jj;
    float4 bb = cbox[jj];
    float ltx = fmaxf(bi.x, bb.x), lty = fmaxf(bi.y, bb.y);
    float rbx = fminf(bi.z, bb.z), rby = fminf(bi.w, bb.w);
    float wx = fmaxf(rbx - ltx, 0.f), wy = fmaxf(rby - lty, 0.f);
    float inter = wx * wy;
    float uni = (ai + carea[jj]) - inter;      // same op order as reference
    float iou = inter / fmaxf(uni, 1e-9f);     // IEEE div, matches numpy
    bool sup = (iou > 0.5f) && (jg < N_ANCH);
    bool cond = hi ? (jg > i) : (jg < i);
    w |= (u64)(sup && cond) << jj;
  }
  if (hi) {
    mask[(u64)i * CBLK + cb] = w;                // row word, above diagonal
  } else {
    wlo_t[((u64)d * CBLK + rb) * 64 + (i & 63)] = w;  // transposed col word
  }
}

// PIPELINED NMS — R12 structure + T14 async-STAGE consume via LDS:
// consume tiles persist across iterations in LDS (not registers — R13/R15
// proved cross-iteration per-lane arrays get scratch-demoted). Per consume
// wave, per iteration: (1) ISSUE group g's 24 ungated loads into locals
// (addresses depend only on g); (2) APPLY group g-1 from the LDS stage
// (24 ds_read_b64 + gate vs keepw + atomicOr rem) — this work hides the
// loads' flight; (3) WRITE-LATE: vmcnt (compiler-inserted) + 24 ds_write
// into the stage. The barrier's lgkmcnt(0) publishes the writes. All
// register live ranges are intra-branch.
//
// Coverage of (w, c), w < c < VB (disjoint, exhaustive):
//   same group       : 4 fixpoints + coupling ballots s1/s2/s3
//   c in 4g+4..4g+7  : carry bank P[4] (ballots over wlo_t d=1..7), land g+1
//   c >= 4g+8        : consume — staged at g, applied at g+1 (L half
//     cols 4g+8..4g+71; H half 4g+72.. only when VB>72, synchronous gated)
// Races: apply at iter X writes rem[c >= 4X+4]; wave0 reads rem[4X..4X+3]
// — disjoint. keepw written at g, first read at g+1 (barrier between).
// Barriers drain LDS only (lgkmcnt) — global loads stay in flight.
__global__ void __launch_bounds__(768, 1) nms_kernel(const float4* __restrict__ sbox,
                                                     const float* __restrict__ sscore,
                                                     const u64* __restrict__ mask,
                                                     const u64* __restrict__ wlo_t,
                                                     float* __restrict__ out) {
  __shared__ u64 keepw[CBLK + 4];
  __shared__ u64 rem[CBLK + 4];
  __shared__ u64 stage[11][24][64];              // 132 KB consume tiles
  int tid = threadIdx.x;
  int wave = tid >> 6, lane = tid & 63;

  // ---- n_valid via 2-round probe (redundant in every wave — same result)
  float s0 = sscore[lane * 132];                 // 63*132 = 8316 < 8400
  u64 pb = __ballot(s0 >= SCORE_THR);
  int cnt1 = (int)__popcll(pb);
  int n_valid = 0;
  if (cnt1 > 0) {
    int a = (cnt1 - 1) * 132 + 1;                // rows < a known valid
    int i1 = a + 3 * lane;
    float t1 = (i1 + 0 < N_ANCH) ? sscore[i1 + 0] : -1.f;
    float t2 = (i1 + 1 < N_ANCH) ? sscore[i1 + 1] : -1.f;
    float t3 = (i1 + 2 < N_ANCH) ? sscore[i1 + 2] : -1.f;
    u64 q1 = __ballot(t1 >= SCORE_THR);
    u64 q2 = __ballot(t2 >= SCORE_THR);
    u64 q3 = __ballot(t3 >= SCORE_THR);
    n_valid = a + (int)__popcll(q1) + (int)__popcll(q2) + (int)__popcll(q3);
  }
  int VB = (n_valid + 63) >> 6;                  // number of valid 64-blocks
  int NG = (VB + 3) >> 2;                        // 256-row iterations

  for (int b = tid; b < CBLK + 4; b += 768) { keepw[b] = 0; rem[b] = 0; }

  // ---- consume-wave row split: 11 waves x 24 rows (last wave 16)
  int rs = (wave - 1) * 24;
  int nr = 256 - rs; if (nr > 24) nr = 24; if (nr < 0) nr = 0;

  // ---- wave-0 load set per group (26 u64, all coalesced wlo_t reads):
  //  [0..3]  Lkk = wt(0, 4g+k)            diag (word k vs rows k)
  //  [4] L10=wt(1,4g+1)  [5] L20=wt(2,4g+2)  [6] L21=wt(1,4g+2)
  //  [7] L30=wt(3,4g+3)  [8] L31=wt(2,4g+3)  [9] L32=wt(1,4g+3)
  //  [10+4m+j] X[m][j] = wt(4+m-j, 4g+4+m)   carries to cols 4g+4..4g+7
  u64 cur[26], nxt[26];
  auto wt = [&](int d, int b) -> u64 {
    return wlo_t[((u64)d * CBLK + b) * 64 + lane];
  };
  auto load_w0 = [&](int g, u64* R) {
    int b = 4 * g;                               // b < VB guaranteed by caller
    bool k1 = (b + 1 < VB), k2 = (b + 2 < VB), k3 = (b + 3 < VB);
    R[0] = wt(0, b);
    R[1] = k1 ? wt(0, b + 1) : 0ull;
    R[2] = k2 ? wt(0, b + 2) : 0ull;
    R[3] = k3 ? wt(0, b + 3) : 0ull;
    R[4] = k1 ? wt(1, b + 1) : 0ull;
    R[5] = k2 ? wt(2, b + 2) : 0ull;
    R[6] = k2 ? wt(1, b + 2) : 0ull;
    R[7] = k3 ? wt(3, b + 3) : 0ull;
    R[8] = k3 ? wt(2, b + 3) : 0ull;
    R[9] = k3 ? wt(1, b + 3) : 0ull;
    #pragma unroll
    for (int m = 0; m < 4; ++m) {
      int c = b + 4 + m;
      bool ok = (c < VB);
      #pragma unroll
      for (int j = 0; j < 4; ++j)
        R[10 + m * 4 + j] = ok ? wt(4 + m - j, c) : 0ull;
    }
  };
  // Two independent ballots per round (covered vs dead) — minimal chain.
  auto fixpoint = [&](u64 colw, u64 act) -> u64 {
    u64 U = act, K = 0;
    while (U) {
      u64 covered = __ballot((colw & U) != 0ull);  // indep of dead
      u64 dead    = __ballot((colw & K) != 0ull);  // indep of covered
      u64 nk = U & ~covered & ~dead;               // definite keepers
      K |= nk;
      U &= ~(nk | dead);
    }
    return K;
  };

  u64 P0 = 0, P1 = 0, P2 = 0, P3 = 0;            // carry bank -> cols 4g..4g+3

  if (wave == 0 && NG > 0) load_w0(0, cur);

  for (int g = 0; g < NG; ++g) {
    // one barrier per iteration; LDS-only drain — global loads stay in flight
    asm volatile("s_waitcnt lgkmcnt(0)\ns_barrier" ::: "memory");

    if (wave == 0) {
      __builtin_amdgcn_s_setprio(1);             // favor the serial scan wave
      int b = 4 * g;
      u64 r0 = rem[b], r1 = rem[b + 1], r2 = rem[b + 2], r3 = rem[b + 3];
      // rotate double buffer; issue next group's 26 loads immediately
      if (g > 0) {
        #pragma unroll
        for (int i = 0; i < 26; ++i) cur[i] = nxt[i];
      }
      if (g + 1 < NG) load_w0(g + 1, nxt);

      int remn = n_valid - b * 64;
      u64 vm0, vm1, vm2, vm3;
      {
        int m0 = remn, m1 = remn - 64, m2 = remn - 128, m3 = remn - 192;
        vm0 = (m0 >= 64) ? ~0ull : ((m0 <= 0) ? 0ull : ((1ull << m0) - 1ull));
        vm1 = (m1 >= 64) ? ~0ull : ((m1 <= 0) ? 0ull : ((1ull << m1) - 1ull));
        vm2 = (m2 >= 64) ? ~0ull : ((m2 <= 0) ? 0ull : ((1ull << m2) - 1ull));
        vm3 = (m3 >= 64) ? ~0ull : ((m3 <= 0) ? 0ull : ((1ull << m3) - 1ull));
      }
      u64 act0 = vm0 & ~(rfl64(r0) | P0);
      u64 act1 = vm1 & ~(rfl64(r1) | P1);
      u64 act2 = vm2 & ~(rfl64(r2) | P2);
      u64 act3 = vm3 & ~(rfl64(r3) | P3);

      // ---- 4 sequential fixpoints with in-register coupling
      u64 kw0 = fixpoint(cur[0], act0);
      u64 s1 = __ballot((cur[4] & kw0) != 0ull);
      u64 kw1 = fixpoint(cur[1], act1 & ~s1);
      u64 s2 = __ballot(((cur[5] & kw0) | (cur[6] & kw1)) != 0ull);
      u64 kw2 = fixpoint(cur[2], act2 & ~s2);
      u64 s3 = __ballot(((cur[7] & kw0) | (cur[8] & kw1) | (cur[9] & kw2)) != 0ull);
      u64 kw3 = fixpoint(cur[3], act3 & ~s3);

      if (lane == 0) {
        keepw[b] = kw0; keepw[b + 1] = kw1;
        keepw[b + 2] = kw2; keepw[b + 3] = kw3;
      }

      // ---- carry bank: group g keepers -> cols 4g+4..4g+7 (4 ballots)
      P0 = __ballot(((cur[10] & kw0) | (cur[11] & kw1) |
                     (cur[12] & kw2) | (cur[13] & kw3)) != 0ull);
      P1 = __ballot(((cur[14] & kw0) | (cur[15] & kw1) |
                     (cur[16] & kw2) | (cur[17] & kw3)) != 0ull);
      P2 = __ballot(((cur[18] & kw0) | (cur[19] & kw1) |
                     (cur[20] & kw2) | (cur[21] & kw3)) != 0ull);
      P3 = __ballot(((cur[22] & kw0) | (cur[23] & kw1) |
                     (cur[24] & kw2) | (cur[25] & kw3)) != 0ull);
      __builtin_amdgcn_s_setprio(0);             // yield while others consume
    } else if (nr > 0) {
      int w = wave - 1;
      // ---- 1. ISSUE ungated loads for group g (locals, intra-branch live)
      u64 tl[24];
      int base2 = 4 * g + 8;
      bool issued = (base2 < VB);
      if (issued) {
        const u64* pr2 = mask + (u64)(256 * g + rs) * CBLK;
        int cL2 = base2 + lane;
        bool ok2 = (cL2 < VB);
        #pragma unroll
        for (int r = 0; r < 24; ++r) {
          bool rok = (r < nr) && ((256 * g + rs + r) < N_ANCH);
          tl[r] = (ok2 && rok) ? pr2[(u64)r * CBLK + cL2] : 0ull;
        }
      }
      // ---- 2. APPLY group e = g-1 from the LDS stage (hides load flight)
      if (g >= 1) {
        int e = g - 1;
        int base = 4 * e + 8;
        if (base < VB) {
          int wi = rs >> 6, sh = rs & 63;
          u64 lo = keepw[4 * e + wi];
          u64 hi = (sh + nr > 64 && wi < 3) ? keepw[4 * e + wi + 1] : 0ull;
          u64 window = sh ? ((lo >> sh) | (hi << (64 - sh))) : lo;
          window = rfl64(window);
          int cL = base + lane;
          bool okL = (cL < VB);
          u64 acc = 0;
          #pragma unroll
          for (int r = 0; r < 24; ++r) {
            u64 sm = (u64)0 - ((r < nr) ? ((window >> r) & 1ull) : 0ull);
            acc |= stage[w][r][lane] & sm;       // staged at g-1, stale->gated
          }
          if (okL && acc) atomicOr((unsigned long long*)&rem[cL], acc);
          // H half (cols base+64..): only when VB > 72 — synchronous gated.
          if (base + 64 < VB) {
            int cH = cL + 64;
            bool okH = (cH < VB);
            const u64* pr = mask + (u64)(256 * e + rs) * CBLK;
            u64 acc2 = 0;
            #pragma unroll
            for (int r = 0; r < 24; ++r) {
              bool bit = (r < nr) && (((window >> r) & 1ull) != 0ull);
              bool rok = (256 * e + rs + r) < N_ANCH;
              u64 v = (bit && okH && rok) ? pr[(u64)r * CBLK + cH] : 0ull;
              acc2 |= v;
            }
            if (okH && acc2) atomicOr((unsigned long long*)&rem[cH], acc2);
          }
        }
      }
      // ---- 3. WRITE-LATE: park group g's tiles in LDS (vmcnt inserted by
      // compiler before each ds_write; barrier's lgkmcnt(0) publishes them)
      if (issued) {
        #pragma unroll
        for (int r = 0; r < 24; ++r) stage[w][r][lane] = tl[r];
      }
    }
  }
  __syncthreads();

  // ---- fused masked output (768 threads)
  for (int r2 = tid; r2 < N_ANCH; r2 += 768) {
    u64 kv = keepw[r2 >> 6];
    bool kp = (kv >> (r2 & 63)) & 1ull;
    float4 b4 = sbox[r2];
    float sc = sscore[r2];
    float* o = out + r2 * 5;
    o[0] = kp ? b4.x : 0.f;
    o[1] = kp ? b4.y : 0.f;
    o[2] = kp ? b4.z : 0.f;
    o[3] = kp ? b4.w : 0.f;
    o[4] = kp ? sc : 0.f;
  }
}

extern "C" void kernel_launch(void* const* d_in, const int* in_sizes, int n_in,
                              void* d_out, int out_size, void* d_ws, size_t ws_size,
                              hipStream_t stream) {
  const float* raw = (const float*)d_in[0];
  float* out = (float*)d_out;
  char* ws = (char*)d_ws;
  // ws layout: sbox (8448*16 B) | sscore (8448*4 B) | mask (8400*132*8 B)
  //          | wlo_t (8*132*64*8 B)  ≈ 9.58 MB total
  float4* sbox = (float4*)ws;
  float* sscore = (float*)(ws + 8448 * 16);
  u64* mask = (u64*)(ws + 8448 * 16 + 8448 * 4);
  u64* wlo_t = (u64*)(ws + 8448 * 16 + 8448 * 4 + (size_t)N_ANCH * CBLK * 8);

  rank_kernel<<<525, 256, 0, stream>>>(raw, sbox, sscore);
  mask_kernel<<<dim3(CBLK, 33), 256, 0, stream>>>(sbox, sscore, mask, wlo_t);
  nms_kernel<<<1, 768, 0, stream>>>(sbox, sscore, mask, wlo_t, out);
}

// Round 17
// 129.556 us; speedup vs baseline: 2.3774x; 2.3774x over previous
//
#include <hip/hip_runtime.h>
#include <cstdint>

#define N_ANCH 8400
#define CBLK 132              // ceil(8400/64)
#define SCORE_THR 0.5f
#define NDIAG 8               // wlo_t diagonals 0..7

typedef unsigned long long u64;
typedef unsigned int u32;

// Sort key: ascending sort == (valid score descending, then index ascending,
// invalid last by index ascending) — exactly matches
// argsort(-where(valid, s, -inf)) with stable ties.
__device__ __forceinline__ u64 sort_key(float s, int idx) {
  u32 k32 = (s >= SCORE_THR) ? ~__float_as_uint(s) : 0xFFFFFFFFu;
  return ((u64)k32 << 32) | (u32)idx;
}

// Force a wave-uniform u64 into SGPRs.
__device__ __forceinline__ u64 rfl64(u64 v) {
  u32 lo = (u32)__builtin_amdgcn_readfirstlane((int)(u32)v);
  u32 hi = (u32)__builtin_amdgcn_readfirstlane((int)(u32)(v >> 32));
  return ((u64)hi << 32) | lo;
}

// 4 rows per wave; scores scanned as float4 (33 iters, 4x fewer loads).
__global__ void __launch_bounds__(256) rank_kernel(const float* __restrict__ raw,
                                                   float4* __restrict__ sbox,
                                                   float* __restrict__ sscore) {
  #pragma clang fp contract(off)
  int tid = blockIdx.x * 256 + threadIdx.x;
  int wid = tid >> 6, lane = tid & 63;
  int base = wid * 4;                            // 525 blocks -> base <= 8396
  const float* sc = raw + 4 * N_ANCH;
  float4 sv = *(const float4*)(sc + base);       // wave-uniform broadcast load
  u64 k0 = sort_key(sv.x, base),     k1 = sort_key(sv.y, base + 1);
  u64 k2 = sort_key(sv.z, base + 2), k3 = sort_key(sv.w, base + 3);
  int c0 = 0, c1 = 0, c2 = 0, c3 = 0;
  for (int it = 0; it < 33; ++it) {
    int j = it * 256 + (lane << 2);              // multiple of 4; j+3 <= 8399
    if (j < N_ANCH) {
      float4 q = *(const float4*)(sc + j);
      u64 a0 = sort_key(q.x, j),     a1 = sort_key(q.y, j + 1);
      u64 a2 = sort_key(q.z, j + 2), a3 = sort_key(q.w, j + 3);
      c0 += (a0 < k0) + (a1 < k0) + (a2 < k0) + (a3 < k0);
      c1 += (a0 < k1) + (a1 < k1) + (a2 < k1) + (a3 < k1);
      c2 += (a0 < k2) + (a1 < k2) + (a2 < k2) + (a3 < k2);
      c3 += (a0 < k3) + (a1 < k3) + (a2 < k3) + (a3 < k3);
    }
  }
  #pragma unroll
  for (int d = 1; d < 64; d <<= 1) {
    c0 += __shfl_xor(c0, d, 64); c1 += __shfl_xor(c1, d, 64);
    c2 += __shfl_xor(c2, d, 64); c3 += __shfl_xor(c3, d, 64);
  }
  if (lane < 4) {
    int row = base + lane;
    int cnt = (lane == 0) ? c0 : (lane == 1) ? c1 : (lane == 2) ? c2 : c3;
    float s = (lane == 0) ? sv.x : (lane == 1) ? sv.y : (lane == 2) ? sv.z : sv.w;
    float cx = raw[row], cy = raw[N_ANCH + row];
    float w = raw[2 * N_ANCH + row], h = raw[3 * N_ANCH + row];
    float hw = w * 0.5f, hh = h * 0.5f;
    sbox[cnt] = make_float4(cx - hw, cy - hh, cx + hw, cy + hh);
    sscore[cnt] = s;
  }
}

// Suppression bitmask, two output layouts; only the NEEDED word per cell
// (~25% less inner-loop VALU than computing both):
//   ABOVE diagonal (cb > i>>6): wHi (row word, "boxes I suppress") in
//     mask[i*CBLK+cb]. Read by nms consume (distance >= 8 only).
//   NEAR diagonal (0 <= d = (i>>6)-cb <= 7): wLo (COLUMN word) TRANSPOSED
//     in wlo_t[d][i>>6][i&63] — contiguous in lane (4 lines per wave0 read).
//   d > 7: dead (band skip).
__global__ void __launch_bounds__(256) mask_kernel(const float4* __restrict__ sbox,
                                                   const float* __restrict__ sscore,
                                                   u64* __restrict__ mask,
                                                   u64* __restrict__ wlo_t) {
  #pragma clang fp contract(off)
  int cb = blockIdx.x;
  int i0 = blockIdx.y * 256;
  if (cb + 7 < (i0 >> 6)) return;                // below-diagonal band skip
  if (!(sscore[i0] >= SCORE_THR)) return;        // whole row-block invalid
  if (!(sscore[cb * 64] >= SCORE_THR)) return;   // whole col-block invalid
  int t = threadIdx.x;
  __shared__ float4 cbox[64];
  __shared__ float carea[64];
  int j0 = cb * 64;
  if (t < 64) {
    int j = j0 + t;
    float4 bj = (j < N_ANCH) ? sbox[j] : make_float4(0.f, 0.f, 0.f, 0.f);
    cbox[t] = bj;
    carea[t] = (bj.z - bj.x) * (bj.w - bj.y);
  }
  __syncthreads();
  int i = i0 + t;
  if (i >= N_ANCH) return;
  int rb = i >> 6;
  int d = rb - cb;
  if (d >= NDIAG) return;                        // thread-level band skip
  bool hi = (d < 0);                             // which word this cell needs
  float4 bi = sbox[i];
  float ai = (bi.z - bi.x) * (bi.w - bi.y);
  u64 w = 0;
  for (int jj = 0; jj < 64; ++jj) {
    int jg = j0 + jj;
    float4 bb = cbox[jj];
    float ltx = fmaxf(bi.x, bb.x), lty = fmaxf(bi.y, bb.y);
    float rbx = fminf(bi.z, bb.z), rby = fminf(bi.w, bb.w);
    float wx = fmaxf(rbx - ltx, 0.f), wy = fmaxf(rby - lty, 0.f);
    float inter = wx * wy;
    float uni = (ai + carea[jj]) - inter;      // same op order as reference
    float iou = inter / fmaxf(uni, 1e-9f);     // IEEE div, matches numpy
    bool sup = (iou > 0.5f) && (jg < N_ANCH);
    bool cond = hi ? (jg > i) : (jg < i);
    w |= (u64)(sup && cond) << jj;
  }
  if (hi) {
    mask[(u64)i * CBLK + cb] = w;                // row word, above diagonal
  } else {
    wlo_t[((u64)d * CBLK + rb) * 64 + (i & 63)] = w;  // transposed col word
  }
}

// PIPELINED NMS — the proven R12 structure (measured 40.6us, VGPR 84, no
// spill). 4 words (256 rows)/iter; wave 0 runs 4 sequential dual-ballot
// fixpoints with in-register coupling + a 4-col carry bank; waves 1-11 do
// same-iteration keeper-filtered consume (24 rows each, gated at load time
// — no persistent arrays, all live ranges intra-branch).
//
// Session post-mortem (R13-R16): per-word cost fits T = F + w*words with
// F~0.6us, w~0.45us/word — lag-consume variants predicted gains from a
// per-iteration comparison of differently-sized iterations (bookkeeping
// error) and their cross-iteration tile arrays were scratch-demoted
// (identical +131KB WRITE_SIZE fingerprint in R13/R15/R16).
//
// Coverage of pair (w, c), w < c < VB (disjoint, exhaustive):
//   c in same group  : 4 fixpoints + coupling ballots s1/s2/s3
//   c in 4g+4..4g+7  : carry bank P[4] — ballots over wlo_t d=1..7
//   c >= 4g+8        : keeper-filtered consume at iter g+1 (waves 1-11)
// Races: consume at iter X writes rem[c >= 4X+4]; wave0 reads rem[4X..4X+3]
// — disjoint. keepw written at g, read at g+1 (barrier between).
// Barriers drain LDS only (lgkmcnt) — globals stay in flight.
__global__ void __launch_bounds__(768, 1) nms_kernel(const float4* __restrict__ sbox,
                                                     const float* __restrict__ sscore,
                                                     const u64* __restrict__ mask,
                                                     const u64* __restrict__ wlo_t,
                                                     float* __restrict__ out) {
  __shared__ u64 keepw[CBLK + 4];
  __shared__ u64 rem[CBLK + 4];
  int tid = threadIdx.x;
  int wave = tid >> 6, lane = tid & 63;

  // ---- n_valid via 2-round probe (redundant in every wave — same result)
  float s0 = sscore[lane * 132];                 // 63*132 = 8316 < 8400
  u64 pb = __ballot(s0 >= SCORE_THR);
  int cnt1 = (int)__popcll(pb);
  int n_valid = 0;
  if (cnt1 > 0) {
    int a = (cnt1 - 1) * 132 + 1;                // rows < a known valid
    int i1 = a + 3 * lane;
    float t1 = (i1 + 0 < N_ANCH) ? sscore[i1 + 0] : -1.f;
    float t2 = (i1 + 1 < N_ANCH) ? sscore[i1 + 1] : -1.f;
    float t3 = (i1 + 2 < N_ANCH) ? sscore[i1 + 2] : -1.f;
    u64 q1 = __ballot(t1 >= SCORE_THR);
    u64 q2 = __ballot(t2 >= SCORE_THR);
    u64 q3 = __ballot(t3 >= SCORE_THR);
    n_valid = a + (int)__popcll(q1) + (int)__popcll(q2) + (int)__popcll(q3);
  }
  int VB = (n_valid + 63) >> 6;                  // number of valid 64-blocks
  int NG = (VB + 3) >> 2;                        // 256-row iterations

  for (int b = tid; b < CBLK + 4; b += 768) { keepw[b] = 0; rem[b] = 0; }

  // ---- consume-wave row split: 11 waves x 24 rows (last wave 16)
  int rs = (wave - 1) * 24;
  int nr = 256 - rs; if (nr > 24) nr = 24; if (nr < 0) nr = 0;

  // ---- wave-0 load set per group (26 u64, all coalesced wlo_t reads):
  //  [0..3]  Lkk = wt(0, 4g+k)            diag (word k vs rows k)
  //  [4] L10=wt(1,4g+1)  [5] L20=wt(2,4g+2)  [6] L21=wt(1,4g+2)
  //  [7] L30=wt(3,4g+3)  [8] L31=wt(2,4g+3)  [9] L32=wt(1,4g+3)
  //  [10+4m+j] X[m][j] = wt(4+m-j, 4g+4+m)   carries to cols 4g+4..4g+7
  u64 cur[26], nxt[26];
  auto wt = [&](int d, int b) -> u64 {
    return wlo_t[((u64)d * CBLK + b) * 64 + lane];
  };
  auto load_w0 = [&](int g, u64* R) {
    int b = 4 * g;                               // b < VB guaranteed by caller
    bool k1 = (b + 1 < VB), k2 = (b + 2 < VB), k3 = (b + 3 < VB);
    R[0] = wt(0, b);
    R[1] = k1 ? wt(0, b + 1) : 0ull;
    R[2] = k2 ? wt(0, b + 2) : 0ull;
    R[3] = k3 ? wt(0, b + 3) : 0ull;
    R[4] = k1 ? wt(1, b + 1) : 0ull;
    R[5] = k2 ? wt(2, b + 2) : 0ull;
    R[6] = k2 ? wt(1, b + 2) : 0ull;
    R[7] = k3 ? wt(3, b + 3) : 0ull;
    R[8] = k3 ? wt(2, b + 3) : 0ull;
    R[9] = k3 ? wt(1, b + 3) : 0ull;
    #pragma unroll
    for (int m = 0; m < 4; ++m) {
      int c = b + 4 + m;
      bool ok = (c < VB);
      #pragma unroll
      for (int j = 0; j < 4; ++j)
        R[10 + m * 4 + j] = ok ? wt(4 + m - j, c) : 0ull;
    }
  };
  // Two independent ballots per round (covered vs dead) — minimal chain.
  auto fixpoint = [&](u64 colw, u64 act) -> u64 {
    u64 U = act, K = 0;
    while (U) {
      u64 covered = __ballot((colw & U) != 0ull);  // indep of dead
      u64 dead    = __ballot((colw & K) != 0ull);  // indep of covered
      u64 nk = U & ~covered & ~dead;               // definite keepers
      K |= nk;
      U &= ~(nk | dead);
    }
    return K;
  };

  u64 P0 = 0, P1 = 0, P2 = 0, P3 = 0;            // carry bank -> cols 4g..4g+3

  if (wave == 0 && NG > 0) load_w0(0, cur);

  for (int g = 0; g < NG; ++g) {
    // one barrier per iteration; LDS-only drain — global loads stay in flight
    asm volatile("s_waitcnt lgkmcnt(0)\ns_barrier" ::: "memory");

    if (wave == 0) {
      __builtin_amdgcn_s_setprio(1);             // favor the serial scan wave
      int b = 4 * g;
      u64 r0 = rem[b], r1 = rem[b + 1], r2 = rem[b + 2], r3 = rem[b + 3];
      // rotate double buffer; issue next group's 26 loads immediately
      if (g > 0) {
        #pragma unroll
        for (int i = 0; i < 26; ++i) cur[i] = nxt[i];
      }
      if (g + 1 < NG) load_w0(g + 1, nxt);

      int remn = n_valid - b * 64;
      u64 vm0, vm1, vm2, vm3;
      {
        int m0 = remn, m1 = remn - 64, m2 = remn - 128, m3 = remn - 192;
        vm0 = (m0 >= 64) ? ~0ull : ((m0 <= 0) ? 0ull : ((1ull << m0) - 1ull));
        vm1 = (m1 >= 64) ? ~0ull : ((m1 <= 0) ? 0ull : ((1ull << m1) - 1ull));
        vm2 = (m2 >= 64) ? ~0ull : ((m2 <= 0) ? 0ull : ((1ull << m2) - 1ull));
        vm3 = (m3 >= 64) ? ~0ull : ((m3 <= 0) ? 0ull : ((1ull << m3) - 1ull));
      }
      u64 act0 = vm0 & ~(rfl64(r0) | P0);
      u64 act1 = vm1 & ~(rfl64(r1) | P1);
      u64 act2 = vm2 & ~(rfl64(r2) | P2);
      u64 act3 = vm3 & ~(rfl64(r3) | P3);

      // ---- 4 sequential fixpoints with in-register coupling
      u64 kw0 = fixpoint(cur[0], act0);
      u64 s1 = __ballot((cur[4] & kw0) != 0ull);
      u64 kw1 = fixpoint(cur[1], act1 & ~s1);
      u64 s2 = __ballot(((cur[5] & kw0) | (cur[6] & kw1)) != 0ull);
      u64 kw2 = fixpoint(cur[2], act2 & ~s2);
      u64 s3 = __ballot(((cur[7] & kw0) | (cur[8] & kw1) | (cur[9] & kw2)) != 0ull);
      u64 kw3 = fixpoint(cur[3], act3 & ~s3);

      if (lane == 0) {
        keepw[b] = kw0; keepw[b + 1] = kw1;
        keepw[b + 2] = kw2; keepw[b + 3] = kw3;
      }

      // ---- carry bank: group g keepers -> cols 4g+4..4g+7 (4 ballots)
      P0 = __ballot(((cur[10] & kw0) | (cur[11] & kw1) |
                     (cur[12] & kw2) | (cur[13] & kw3)) != 0ull);
      P1 = __ballot(((cur[14] & kw0) | (cur[15] & kw1) |
                     (cur[16] & kw2) | (cur[17] & kw3)) != 0ull);
      P2 = __ballot(((cur[18] & kw0) | (cur[19] & kw1) |
                     (cur[20] & kw2) | (cur[21] & kw3)) != 0ull);
      P3 = __ballot(((cur[22] & kw0) | (cur[23] & kw1) |
                     (cur[24] & kw2) | (cur[25] & kw3)) != 0ull);
      __builtin_amdgcn_s_setprio(0);             // yield while others consume
    } else if (g >= 1 && nr > 0) {
      // ---- same-iteration keeper-filtered consume of group e = g-1
      int e = g - 1;
      int base = 4 * e + 8;
      if (base < VB) {
        // keep-bit window for rows rs..rs+nr-1 of the 256-row group
        int wi = rs >> 6, sh = rs & 63;
        u64 lo = keepw[4 * e + wi];
        u64 hi = (sh + nr > 64 && wi < 3) ? keepw[4 * e + wi + 1] : 0ull;
        u64 window = sh ? ((lo >> sh) | (hi << (64 - sh))) : lo;
        window = rfl64(window);
        const u64* pr = mask + (u64)(256 * e + rs) * CBLK;
        int cL = base + lane;
        bool okL = (cL < VB);
        u64 acc = 0;
        #pragma unroll
        for (int r = 0; r < 24; ++r) {
          bool bit = (r < nr) && (((window >> r) & 1ull) != 0ull);
          u64 v = (bit && okL) ? pr[(u64)r * CBLK + cL] : 0ull;
          acc |= v;
        }
        if (okL && acc) atomicOr((unsigned long long*)&rem[cL], acc);
        if (base + 64 < VB) {                    // H half exists at all?
          int cH = cL + 64;
          bool okH = (cH < VB);
          u64 acc2 = 0;
          #pragma unroll
          for (int r = 0; r < 24; ++r) {
            bool bit = (r < nr) && (((window >> r) & 1ull) != 0ull);
            u64 v = (bit && okH) ? pr[(u64)r * CBLK + cH] : 0ull;
            acc2 |= v;
          }
          if (okH && acc2) atomicOr((unsigned long long*)&rem[cH], acc2);
        }
      }
    }
  }
  __syncthreads();

  // ---- fused masked output (768 threads)
  for (int r2 = tid; r2 < N_ANCH; r2 += 768) {
    u64 kv = keepw[r2 >> 6];
    bool kp = (kv >> (r2 & 63)) & 1ull;
    float4 b4 = sbox[r2];
    float sc = sscore[r2];
    float* o = out + r2 * 5;
    o[0] = kp ? b4.x : 0.f;
    o[1] = kp ? b4.y : 0.f;
    o[2] = kp ? b4.z : 0.f;
    o[3] = kp ? b4.w : 0.f;
    o[4] = kp ? sc : 0.f;
  }
}

extern "C" void kernel_launch(void* const* d_in, const int* in_sizes, int n_in,
                              void* d_out, int out_size, void* d_ws, size_t ws_size,
                              hipStream_t stream) {
  const float* raw = (const float*)d_in[0];
  float* out = (float*)d_out;
  char* ws = (char*)d_ws;
  // ws layout: sbox (8448*16 B) | sscore (8448*4 B) | mask (8400*132*8 B)
  //          | wlo_t (8*132*64*8 B)  ≈ 9.58 MB total
  float4* sbox = (float4*)ws;
  float* sscore = (float*)(ws + 8448 * 16);
  u64* mask = (u64*)(ws + 8448 * 16 + 8448 * 4);
  u64* wlo_t = (u64*)(ws + 8448 * 16 + 8448 * 4 + (size_t)N_ANCH * CBLK * 8);

  rank_kernel<<<525, 256, 0, stream>>>(raw, sbox, sscore);
  mask_kernel<<<dim3(CBLK, 33), 256, 0, stream>>>(sbox, sscore, mask, wlo_t);
  nms_kernel<<<1, 768, 0, stream>>>(sbox, sscore, mask, wlo_t, out);
}